// Round 6
// baseline (191.273 us; speedup 1.0000x reference)
//
#include <hip/hip_runtime.h>
#include <hip/hip_bf16.h>

#define DD   4096   // hidden dim
#define NE   8      // experts
#define NR   16     // lora rank
#define NTOK 8192   // B*S
#define NDO  4096   // output dim
// SCALING = 16/16 = 1.0

typedef __attribute__((ext_vector_type(8))) __bf16 bf16x8;
typedef __attribute__((ext_vector_type(4))) float  f32x4;

__device__ __forceinline__ bf16x8 to_bf16x8(float4 a, float4 b) {
    bf16x8 r;
    r[0] = (__bf16)a.x; r[1] = (__bf16)a.y; r[2] = (__bf16)a.z; r[3] = (__bf16)a.w;
    r[4] = (__bf16)b.x; r[5] = (__bf16)b.y; r[6] = (__bf16)b.z; r[7] = (__bf16)b.w;
    return r;
}

// ---------------- k1: routing (f64 logits) + expert binning ----------------
// VERBATIM round-1 version (empirically ~45us by bench subtraction; every
// rewrite since landed at ~104us). 512 blocks x 256 threads; wave = 4 tokens.
__global__ __launch_bounds__(256) void k_route(const float* __restrict__ x,
                                               const float* __restrict__ rw,
                                               float* __restrict__ w_arr,
                                               int*   __restrict__ token_list,
                                               int*   __restrict__ count) {
    const int wave = threadIdx.x >> 6;
    const int lane = threadIdx.x & 63;
    const int t0   = blockIdx.x * 16 + wave * 4;
    const float* xp = x + (size_t)t0 * DD;

    double acc[4][NE];
    #pragma unroll
    for (int t = 0; t < 4; t++)
        #pragma unroll
        for (int e = 0; e < NE; e++) acc[t][e] = 0.0;

    // lane covers d = (i*64 + lane)*4 .. +3  -> coalesced float4, full D
    for (int i = 0; i < 16; i++) {
        const int d4 = (i * 64 + lane) * 4;
        double xd[4][4];
        #pragma unroll
        for (int t = 0; t < 4; t++) {
            const float4 xv = *(const float4*)(xp + (size_t)t * DD + d4);
            xd[t][0] = xv.x; xd[t][1] = xv.y; xd[t][2] = xv.z; xd[t][3] = xv.w;
        }
        #pragma unroll
        for (int e = 0; e < NE; e++) {
            const float4 wv = *(const float4*)(rw + (size_t)e * DD + d4);
            const double w0 = wv.x, w1 = wv.y, w2 = wv.z, w3 = wv.w;
            #pragma unroll
            for (int t = 0; t < 4; t++) {
                acc[t][e] = fma(xd[t][0], w0, acc[t][e]);
                acc[t][e] = fma(xd[t][1], w1, acc[t][e]);
                acc[t][e] = fma(xd[t][2], w2, acc[t][e]);
                acc[t][e] = fma(xd[t][3], w3, acc[t][e]);
            }
        }
    }

    // full 64-lane butterfly (f64): every lane ends with complete sums
    #pragma unroll
    for (int off = 32; off > 0; off >>= 1) {
        #pragma unroll
        for (int t = 0; t < 4; t++)
            #pragma unroll
            for (int e = 0; e < NE; e++)
                acc[t][e] += __shfl_xor(acc[t][e], off, 64);
    }

    // lanes 0..3: argmax (first max, matches top_k tie-break) + scatter
    #pragma unroll
    for (int tt = 0; tt < 4; tt++) {
        if (lane == tt) {
            double best = acc[tt][0]; int be = 0;
            #pragma unroll
            for (int e = 1; e < NE; e++)
                if (acc[tt][e] > best) { best = acc[tt][e]; be = e; }
            const int tok = t0 + tt;
            w_arr[tok] = (float)best;
            const int pos = atomicAdd(&count[be], 1);
            token_list[be * NTOK + pos] = tok;
        }
    }
}

// ---------------- k2: wh[tok][r] = w * (x . A[e]^T)  (bf16 out) ----------------
// v2: 32-token tile, 16 waves (1024 thr), wave = K-slice 256, 2 token-subtiles
// sharing one A B-frag per k-chunk. A L2 traffic halved; 4 waves/SIMD live.
__global__ __launch_bounds__(1024) void k_h(const float* __restrict__ x,
                                            const float* __restrict__ Am,
                                            const float* __restrict__ w_arr,
                                            const int*   __restrict__ token_list,
                                            const int*   __restrict__ count,
                                            __hip_bfloat16* __restrict__ wh) {
    const int e    = blockIdx.x >> 6;         // 8 experts x 64 slots (cap 2048 tok/e)
    const int g    = blockIdx.x & 63;
    const int cnt  = count[e];
    const int base = g * 32;
    if (base >= cnt) return;

    const int wv   = threadIdx.x >> 6;        // 0..15
    const int lane = threadIdx.x & 63;
    const int m    = lane & 15;
    const int half = lane >> 4;

    const int i0 = base + m,  i1 = base + 16 + m;
    const int tok0 = (i0 < cnt) ? token_list[e * NTOK + i0] : 0;
    const int tok1 = (i1 < cnt) ? token_list[e * NTOK + i1] : 0;
    const float* xr0  = x + (size_t)tok0 * DD;
    const float* xr1  = x + (size_t)tok1 * DD;
    const float* arow = Am + ((size_t)e * NR + m) * DD;   // B-frag row r = lane&15

    f32x4 acc0 = {0.f,0.f,0.f,0.f}, acc1 = {0.f,0.f,0.f,0.f};
    const int kbase = wv * 256;
    #pragma unroll
    for (int kc = 0; kc < 8; kc++) {
        const int k0 = kbase + kc * 32 + half * 8;
        const bf16x8 bfrag = to_bf16x8(*(const float4*)(arow + k0),
                                       *(const float4*)(arow + k0 + 4));
        const bf16x8 a0 = to_bf16x8(*(const float4*)(xr0 + k0),
                                    *(const float4*)(xr0 + k0 + 4));
        const bf16x8 a1 = to_bf16x8(*(const float4*)(xr1 + k0),
                                    *(const float4*)(xr1 + k0 + 4));
        acc0 = __builtin_amdgcn_mfma_f32_16x16x32_bf16(a0, bfrag, acc0, 0, 0, 0);
        acc1 = __builtin_amdgcn_mfma_f32_16x16x32_bf16(a1, bfrag, acc1, 0, 0, 0);
    }

    // C layout: row = (lane>>4)*4 + reg (token-in-subtile), col = lane&15 (r)
    __shared__ float lds[16][32][17];
    #pragma unroll
    for (int rr = 0; rr < 4; rr++) {
        lds[wv][half * 4 + rr][m]      = acc0[rr];
        lds[wv][16 + half * 4 + rr][m] = acc1[rr];
    }
    __syncthreads();

    if (threadIdx.x < 512) {
        const int t = threadIdx.x >> 4;       // 0..31
        const int r = threadIdx.x & 15;
        const int i2 = base + t;
        if (i2 < cnt) {
            float s = 0.f;
            #pragma unroll
            for (int w = 0; w < 16; w++) s += lds[w][t][r];
            const int tk = token_list[e * NTOK + i2];
            wh[(size_t)tk * NR + r] = (__hip_bfloat16)(s * w_arr[tk]);
        }
    }
}

// ---------------- k3: out = wh . Bw[e]^T ----------------
// v2: block = 16 tokens x FULL 4096 outputs (8 waves x 512 o). a2 gathered once
// per block; grid 1024 (vs 16384) kills dead-block churn.
__global__ __launch_bounds__(512) void k_out(const float* __restrict__ Bw,
                                             const __hip_bfloat16* __restrict__ wh,
                                             const int*   __restrict__ token_list,
                                             const int*   __restrict__ count,
                                             float* __restrict__ out) {
    const int e    = blockIdx.x >> 7;         // 8 experts x 128 slots (cap 2048 tok/e)
    const int slot = blockIdx.x & 127;
    const int cnt  = count[e];
    const int base = slot * 16;
    if (base >= cnt) return;

    const int wv   = threadIdx.x >> 6;        // 0..7
    const int lane = threadIdx.x & 63;
    const int m    = lane & 15;
    const int half = lane >> 4;

    const int  idx   = base + m;
    const bool valid = idx < cnt;
    const int  tok   = valid ? token_list[e * NTOK + idx] : 0;

    // a2 frag: wh[token m][k], k = half*8+j for half<2, zero-padded K=32
    bf16x8 a2;
    if (half < 2 && valid) {
        a2 = *(const bf16x8*)(wh + (size_t)tok * NR + half * 8);
    } else {
        #pragma unroll
        for (int j = 0; j < 8; j++) a2[j] = (__bf16)0.0f;
    }

    int trow[4]; bool vrow[4];
    #pragma unroll
    for (int r = 0; r < 4; r++) {
        const int ir = base + half * 4 + r;
        vrow[r] = ir < cnt;
        trow[r] = vrow[r] ? token_list[e * NTOK + ir] : 0;
    }

    const float* bwe = Bw + (size_t)e * NDO * NR;
    const int h2 = (half < 2) ? half : 0;
    const f32x4 zero4 = {0.f, 0.f, 0.f, 0.f};
    const int ob0 = wv * 512;

    #pragma unroll 4
    for (int ot = 0; ot < 32; ot++) {
        const int obase = ob0 + ot * 16;
        const float* bp = bwe + (size_t)(obase + m) * NR + h2 * 8;
        const float4 p = *(const float4*)(bp);
        const float4 q = *(const float4*)(bp + 4);
        bf16x8 b2 = to_bf16x8(p, q);
        if (half >= 2) {
            #pragma unroll
            for (int j = 0; j < 8; j++) b2[j] = (__bf16)0.0f;
        }
        const f32x4 d = __builtin_amdgcn_mfma_f32_16x16x32_bf16(a2, b2, zero4, 0, 0, 0);
        #pragma unroll
        for (int r = 0; r < 4; r++) {
            if (vrow[r]) out[(size_t)trow[r] * NDO + obase + m] = d[r];
        }
    }
}

// ---------------- launcher ----------------
extern "C" void kernel_launch(void* const* d_in, const int* in_sizes, int n_in,
                              void* d_out, int out_size, void* d_ws, size_t ws_size,
                              hipStream_t stream) {
    const float* x  = (const float*)d_in[0];
    const float* rw = (const float*)d_in[1];
    const float* Am = (const float*)d_in[2];
    const float* Bw = (const float*)d_in[3];
    float* out = (float*)d_out;

    char* ws = (char*)d_ws;
    int*   count      = (int*)ws;                           // 8 ints
    float* w_arr      = (float*)(ws + 512);                 // 8192 f32
    int*   token_list = (int*)(ws + 65536);                 // 8*8192 ints
    __hip_bfloat16* wh = (__hip_bfloat16*)(ws + 65536 + NE * NTOK * 4); // 8192*16 bf16

    hipMemsetAsync(count, 0, 64, stream);
    hipLaunchKernelGGL(k_route, dim3(512),  dim3(256),  0, stream, x, rw, w_arr, token_list, count);
    hipLaunchKernelGGL(k_h,     dim3(512),  dim3(1024), 0, stream, x, Am, w_arr, token_list, count, wh);
    hipLaunchKernelGGL(k_out,   dim3(1024), dim3(512),  0, stream, Bw, wh, token_list, count, out);
}